// Round 1
// baseline (128.619 us; speedup 1.0000x reference)
//
#include <hip/hip_runtime.h>
#include <math.h>

// Model_21775484190778: Gaussian-splat PDE step.
// N=1024 gaussians, K=5 -> S=25600 samples. All fp32.
// Kernel 1: S x N mixture evaluation (dominant, ~500 MFLOP).
// Kernel 2: per-gaussian 4-way MLP stack (~85 MFLOP).

namespace {

constexpr int NG = 1024;          // N
constexpr int K2 = 25;            // K*K
constexpr float DXF = 2.0f / 31.0f;
constexpr float NHALF_LOG2E = -0.72134752044448170367f;  // -0.5 * log2(e)

// ---------------------------------------------------------------------------
// Kernel 1: mixture evaluation.
// grid = 400 blocks x 256 threads. Each block: 64 samples x 4 gaussian-quarters.
// Gaussian table (mx,my,a,b | c,u) staged in LDS (24 KB). Inner-loop gaussian
// index is wave-uniform -> LDS broadcast reads (conflict-free).
// ---------------------------------------------------------------------------
__global__ __launch_bounds__(256) void k_mixture(
    const float* __restrict__ means, const float* __restrict__ uu,
    const float* __restrict__ scaling, const float* __restrict__ transform,
    float* __restrict__ img /* [N][3][25] */)
{
  __shared__ float4 gp[NG];      // mx, my, a, b
  __shared__ float2 gq[NG];      // c, u
  __shared__ float r_us[4][64];
  __shared__ float r_pde[4][64];

  const int tid = threadIdx.x;

  // Stage gaussian table, computing conics on the fly.
  // cov = L L^T, L = [[s0,0],[t0,s1]]; det = s0^2 s1^2
  // conic = [[(t0^2+s1^2)/(s0^2 s1^2), -t0/(s0 s1^2)], [., 1/s1^2]]
  for (int g = tid; g < NG; g += 256) {
    float mx = means[2 * g], my = means[2 * g + 1];
    float s0 = scaling[2 * g], s1 = scaling[2 * g + 1];
    float t0 = transform[g];
    float c  = 1.0f / (s1 * s1);
    float is0 = 1.0f / s0;
    float b  = -t0 * c * is0;
    float a  = (t0 * t0 * c + 1.0f) * is0 * is0;
    gp[g] = make_float4(mx, my, a, b);
    gq[g] = make_float2(c, uu[g]);
  }
  __syncthreads();

  const int sub  = tid >> 6;      // gaussian quarter 0..3 (wave-uniform)
  const int lane = tid & 63;
  const int s  = blockIdx.x * 64 + lane;       // sample id, < 25600
  const int i  = s / K2;
  const int k  = s - i * K2;
  const int kx = k / 5;
  const int ky = k - kx * 5;
  const float sx = means[2 * i]     + (float)(kx - 2) * DXF;
  const float sy = means[2 * i + 1] + (float)(ky - 2) * DXF;

  float us = 0.0f, pde = 0.0f;
  const int g0 = sub * 256;
#pragma unroll 4
  for (int j = 0; j < 256; ++j) {
    const int g = g0 + j;
    float4 p  = gp[g];
    float2 qv = gq[g];
    float dx = sx - p.x, dy = sy - p.y;
    float a = p.z, b = p.w, c = qv.x;
    float Cd0 = a * dx + b * dy;
    float Cd1 = b * dx + c * dy;
    float q   = dx * Cd0 + dy * Cd1;
    float w   = qv.y * exp2f(NHALF_LOG2E * q);   // G * u_j
    us  += w;
    pde += w * (Cd0 * Cd0 + Cd1 * Cd1 - (a + c));
  }
  r_us[sub][lane]  = us;
  r_pde[sub][lane] = pde;
  __syncthreads();

  if (tid < 64) {  // sub==0 thread of each sample; sx/sy already correct
    float U = r_us[0][tid] + r_us[1][tid] + r_us[2][tid] + r_us[3][tid];
    float P = r_pde[0][tid] + r_pde[1][tid] + r_pde[2][tid] + r_pde[3][tid];
    float mask = (fabsf(sx) < 1.0f && fabsf(sy) < 1.0f) ? 1.0f : 0.0f;
    img[i * 75 + k]      = U;     // channel 0: u_s
    img[i * 75 + 25 + k] = P;     // channel 1: pde (laplacian)
    img[i * 75 + 50 + k] = mask;  // channel 2: mask
  }
}

// ---------------------------------------------------------------------------
// Kernel 2: the 4 stacked networks. One block (256 thr) per gaussian.
// conv spans whole KxK patch -> 75-dot per (m,o); then lin1 (80x80 per m),
// then 4 heads. Weights stream from L2 (per-lane conv rows stay L1-resident).
// ---------------------------------------------------------------------------
__global__ __launch_bounds__(256) void k_net(
    const float* __restrict__ img,
    const float* __restrict__ means, const float* __restrict__ uu,
    const float* __restrict__ scaling, const float* __restrict__ transform,
    const float* __restrict__ conv_w, const float* __restrict__ conv_b,
    const float* __restrict__ emb_w, const float* __restrict__ emb_b,
    const float* __restrict__ lin1_w, const float* __restrict__ lin1_b,
    const float* __restrict__ sol_w, const float* __restrict__ sol_b,
    const float* __restrict__ tr_w, const float* __restrict__ tr_b,
    const float* __restrict__ sc_w, const float* __restrict__ sc_b,
    const float* __restrict__ tf_w, const float* __restrict__ tf_b,
    float* __restrict__ out)
{
  const int i = blockIdx.x;
  const int tid = threadIdx.x;

  __shared__ float simg[75];
  __shared__ float sparams[6];   // mx, my, u, s0, s1, t0
  __shared__ float h[320];       // (m,0..79) = concat(y[50], e[30])
  __shared__ float h2[320];

  if (tid < 75) simg[tid] = img[i * 75 + tid];
  if (tid < 6) {
    float v;
    if (tid < 2)       v = means[2 * i + tid];
    else if (tid == 2) v = uu[i];
    else if (tid < 5)  v = scaling[2 * i + (tid - 3)];
    else               v = transform[i];
    sparams[tid] = v;
  }
  __syncthreads();

  // conv: y[m][o] = tanh(sum_chw img*W + b), 200 outputs
  if (tid < 200) {
    const int m = tid / 50, o = tid - m * 50;
    const float* wrow = conv_w + (m * 50 + o) * 75;
    float acc = conv_b[m * 50 + o];
#pragma unroll
    for (int c = 0; c < 75; ++c) acc = fmaf(simg[c], wrow[c], acc);
    h[m * 80 + o] = tanhf(acc);
  }
  // emb: e[m][q] = tanh(sum_p params*W + b), 120 outputs
  if (tid < 120) {
    const int m = tid / 30, q = tid - m * 30;
    float acc = emb_b[m * 30 + q];
#pragma unroll
    for (int p = 0; p < 6; ++p) acc = fmaf(sparams[p], emb_w[(m * 6 + p) * 30 + q], acc);
    h[m * 80 + 50 + q] = tanhf(acc);
  }
  __syncthreads();

  // lin1: h2[m][q] = tanh(sum_j h[m][j] * W[m][j][q] + b), 320 outputs
  for (int idx = tid; idx < 320; idx += 256) {
    const int m = idx / 80, q = idx - m * 80;
    const float* lw = lin1_w + m * 6400 + q;   // stride 80 over j, lane-coalesced in q
    const float* hh = h + m * 80;
    float acc = lin1_b[m * 80 + q];
#pragma unroll 8
    for (int j = 0; j < 80; ++j) acc = fmaf(hh[j], lw[j * 80], acc);
    h2[idx] = tanhf(acc);
  }
  __syncthreads();

  // heads -> out[i][0..5] = (u_new, means_new(2), scaling_new(2), transform_new)
  if (tid < 6) {
    float res;
    if (tid == 0) {
      float acc = sol_b[0];
      for (int j = 0; j < 80; ++j) acc = fmaf(h2[j], sol_w[j], acc);
      res = sparams[2] + acc;
    } else if (tid < 3) {
      const int d = tid - 1;
      float acc = tr_b[d];
      for (int j = 0; j < 80; ++j) acc = fmaf(h2[80 + j], tr_w[j * 2 + d], acc);
      res = sparams[d] + acc;
    } else if (tid < 5) {
      const int d = tid - 3;
      float acc = sc_b[d];
      for (int j = 0; j < 80; ++j) acc = fmaf(h2[160 + j], sc_w[j * 2 + d], acc);
      res = sparams[3 + d] * expf(acc);
    } else {
      float acc = tf_b[0];
      for (int j = 0; j < 80; ++j) acc = fmaf(h2[240 + j], tf_w[j], acc);
      res = sparams[5] + acc;
    }
    out[i * 6 + tid] = res;
  }
}

}  // namespace

extern "C" void kernel_launch(void* const* d_in, const int* in_sizes, int n_in,
                              void* d_out, int out_size, void* d_ws, size_t ws_size,
                              hipStream_t stream) {
  const float* means     = (const float*)d_in[0];
  const float* uu        = (const float*)d_in[1];
  const float* scaling   = (const float*)d_in[2];
  const float* transform = (const float*)d_in[3];
  const float* conv_w    = (const float*)d_in[4];
  const float* conv_b    = (const float*)d_in[5];
  const float* emb_w     = (const float*)d_in[6];
  const float* emb_b     = (const float*)d_in[7];
  const float* lin1_w    = (const float*)d_in[8];
  const float* lin1_b    = (const float*)d_in[9];
  const float* sol_w     = (const float*)d_in[10];
  const float* sol_b     = (const float*)d_in[11];
  const float* tr_w      = (const float*)d_in[12];
  const float* tr_b      = (const float*)d_in[13];
  const float* sc_w      = (const float*)d_in[14];
  const float* sc_b      = (const float*)d_in[15];
  const float* tf_w      = (const float*)d_in[16];
  const float* tf_b      = (const float*)d_in[17];

  float* img = (float*)d_ws;     // 1024*75 floats = 307200 B
  float* out = (float*)d_out;    // 1024*6 floats

  k_mixture<<<400, 256, 0, stream>>>(means, uu, scaling, transform, img);
  k_net<<<1024, 256, 0, stream>>>(img, means, uu, scaling, transform,
                                  conv_w, conv_b, emb_w, emb_b, lin1_w, lin1_b,
                                  sol_w, sol_b, tr_w, tr_b, sc_w, sc_b, tf_w, tf_b,
                                  out);
}

// Round 2
// 121.675 us; speedup vs baseline: 1.0571x; 1.0571x over previous
//
#include <hip/hip_runtime.h>
#include <math.h>

// Model_21775484190778: Gaussian-splat PDE step. N=1024, K=5 -> S=25600 samples.
// R2: coalesce k_net conv (transposed weights), fast tanh/exp (hw v_exp_f32),
// parallel head epilogue.

namespace {

constexpr int NG = 1024;
constexpr int K2 = 25;
constexpr float DXF = 2.0f / 31.0f;
constexpr float NHALF_LOG2E = -0.72134752044448170367f;  // -0.5 * log2(e)
constexpr float TWO_LOG2E   = 2.88539008177792681472f;   //  2.0 * log2(e)
constexpr float LOG2E       = 1.44269504088896340736f;

__device__ __forceinline__ float fast_tanh(float x) {
  x = fminf(9.0f, fmaxf(-9.0f, x));
  float t = __builtin_amdgcn_exp2f(TWO_LOG2E * x);
  return (t - 1.0f) * __builtin_amdgcn_rcpf(t + 1.0f);
}

// ---------------------------------------------------------------------------
// Prep: transpose conv_w (4,50,75) -> cwT (4,75,50) so conv reads are
// lane-coalesced over o.
// ---------------------------------------------------------------------------
__global__ __launch_bounds__(256) void k_prep(
    const float* __restrict__ conv_w, float* __restrict__ cwT)
{
  int idx = blockIdx.x * 256 + threadIdx.x;   // output index (m,c,o)
  if (idx < 4 * 75 * 50) {
    int m = idx / 3750, r = idx - m * 3750;
    int c = r / 50, o = r - c * 50;
    cwT[idx] = conv_w[(m * 50 + o) * 75 + c];
  }
}

// ---------------------------------------------------------------------------
// Kernel 1: mixture evaluation. 400 blocks x 256 thr; block = 64 samples x
// 4 gaussian-quarters; gaussian table in LDS (wave-uniform broadcast reads).
// ---------------------------------------------------------------------------
__global__ __launch_bounds__(256) void k_mixture(
    const float* __restrict__ means, const float* __restrict__ uu,
    const float* __restrict__ scaling, const float* __restrict__ transform,
    float* __restrict__ img /* [N][3][25] */)
{
  __shared__ float4 gp[NG];      // mx, my, a, b
  __shared__ float2 gq[NG];      // c, u
  __shared__ float r_us[4][64];
  __shared__ float r_pde[4][64];

  const int tid = threadIdx.x;

  // conic from L = [[s0,0],[t0,s1]]: a=(t0^2+s1^2)/(s0^2 s1^2), b=-t0/(s0 s1^2), c=1/s1^2
  for (int g = tid; g < NG; g += 256) {
    float mx = means[2 * g], my = means[2 * g + 1];
    float s0 = scaling[2 * g], s1 = scaling[2 * g + 1];
    float t0 = transform[g];
    float c  = 1.0f / (s1 * s1);
    float is0 = 1.0f / s0;
    float b  = -t0 * c * is0;
    float a  = (t0 * t0 * c + 1.0f) * is0 * is0;
    gp[g] = make_float4(mx, my, a, b);
    gq[g] = make_float2(c, uu[g]);
  }
  __syncthreads();

  const int sub  = tid >> 6;
  const int lane = tid & 63;
  const int s  = blockIdx.x * 64 + lane;
  const int i  = s / K2;
  const int k  = s - i * K2;
  const int kx = k / 5;
  const int ky = k - kx * 5;
  const float sx = means[2 * i]     + (float)(kx - 2) * DXF;
  const float sy = means[2 * i + 1] + (float)(ky - 2) * DXF;

  float us = 0.0f, pde = 0.0f;
  const int g0 = sub * 256;
#pragma unroll 4
  for (int j = 0; j < 256; ++j) {
    const int g = g0 + j;
    float4 p  = gp[g];
    float2 qv = gq[g];
    float dx = sx - p.x, dy = sy - p.y;
    float a = p.z, b = p.w, c = qv.x;
    float Cd0 = a * dx + b * dy;
    float Cd1 = b * dx + c * dy;
    float q   = dx * Cd0 + dy * Cd1;
    float w   = qv.y * __builtin_amdgcn_exp2f(NHALF_LOG2E * q);
    us  += w;
    pde += w * (Cd0 * Cd0 + Cd1 * Cd1 - (a + c));
  }
  r_us[sub][lane]  = us;
  r_pde[sub][lane] = pde;
  __syncthreads();

  if (tid < 64) {
    float U = r_us[0][tid] + r_us[1][tid] + r_us[2][tid] + r_us[3][tid];
    float P = r_pde[0][tid] + r_pde[1][tid] + r_pde[2][tid] + r_pde[3][tid];
    float mask = (fabsf(sx) < 1.0f && fabsf(sy) < 1.0f) ? 1.0f : 0.0f;
    img[i * 75 + k]      = U;
    img[i * 75 + 25 + k] = P;
    img[i * 75 + 50 + k] = mask;
  }
}

// ---------------------------------------------------------------------------
// Kernel 2: 4 stacked networks, one block per gaussian (1024 blocks = 4/CU).
// conv reads now coalesced via cwT (m,c,o).
// ---------------------------------------------------------------------------
__global__ __launch_bounds__(256) void k_net(
    const float* __restrict__ img,
    const float* __restrict__ means, const float* __restrict__ uu,
    const float* __restrict__ scaling, const float* __restrict__ transform,
    const float* __restrict__ cwT, const float* __restrict__ conv_b,
    const float* __restrict__ emb_w, const float* __restrict__ emb_b,
    const float* __restrict__ lin1_w, const float* __restrict__ lin1_b,
    const float* __restrict__ sol_w, const float* __restrict__ sol_b,
    const float* __restrict__ tr_w, const float* __restrict__ tr_b,
    const float* __restrict__ sc_w, const float* __restrict__ sc_b,
    const float* __restrict__ tf_w, const float* __restrict__ tf_b,
    float* __restrict__ out)
{
  const int i = blockIdx.x;
  const int tid = threadIdx.x;

  __shared__ float simg[75];
  __shared__ float sparams[6];   // mx, my, u, s0, s1, t0
  __shared__ float h[320];
  __shared__ float h2[320];
  __shared__ float hpart[6][8];

  if (tid < 75) simg[tid] = img[i * 75 + tid];
  if (tid < 6) {
    float v;
    if (tid < 2)       v = means[2 * i + tid];
    else if (tid == 2) v = uu[i];
    else if (tid < 5)  v = scaling[2 * i + (tid - 3)];
    else               v = transform[i];
    sparams[tid] = v;
  }
  __syncthreads();

  // conv: threads 0..199 -> y[m][o]; reads coalesced over o (stride 1)
  if (tid < 200) {
    const int m = tid / 50, o = tid - m * 50;
    const float* w = cwT + m * 3750 + o;     // + c*50
    float acc = conv_b[m * 50 + o];
#pragma unroll
    for (int c = 0; c < 75; ++c) acc = fmaf(simg[c], w[c * 50], acc);
    h[m * 80 + o] = fast_tanh(acc);
  }
  // emb: threads 200..255 strided over 120 outputs (6-FMA each, cheap)
  if (tid >= 200) {
    for (int e = tid - 200; e < 120; e += 56) {
      const int m = e / 30, q = e - m * 30;
      float acc = emb_b[m * 30 + q];
#pragma unroll
      for (int p = 0; p < 6; ++p) acc = fmaf(sparams[p], emb_w[(m * 6 + p) * 30 + q], acc);
      h[m * 80 + 50 + q] = fast_tanh(acc);
    }
  }
  __syncthreads();

  // lin1: 320 outputs; weight reads lane-coalesced over q
  for (int idx = tid; idx < 320; idx += 256) {
    const int m = idx / 80, q = idx - m * 80;
    const float* lw = lin1_w + m * 6400 + q;
    const float* hh = h + m * 80;
    float acc = lin1_b[m * 80 + q];
#pragma unroll 8
    for (int j = 0; j < 80; ++j) acc = fmaf(hh[j], lw[j * 80], acc);
    h2[idx] = fast_tanh(acc);
  }
  __syncthreads();

  // heads: 48 threads = 6 outputs x 8 chunks of 10; uniform inner loop
  if (tid < 48) {
    const int o = tid >> 3, c8 = tid & 7;
    const int m = (o == 0) ? 0 : (o < 3) ? 1 : (o < 5) ? 2 : 3;
    const float* wp; int stride;
    if (o == 0)      { wp = sol_w;            stride = 1; }
    else if (o < 3)  { wp = tr_w + (o - 1);   stride = 2; }
    else if (o < 5)  { wp = sc_w + (o - 3);   stride = 2; }
    else             { wp = tf_w;             stride = 1; }
    const float* hh = h2 + m * 80;
    float acc = 0.0f;
    const int j0 = c8 * 10;
#pragma unroll
    for (int j = 0; j < 10; ++j) acc = fmaf(hh[j0 + j], wp[(j0 + j) * stride], acc);
    hpart[o][c8] = acc;
  }
  __syncthreads();

  if (tid < 6) {
    float acc = 0.0f;
#pragma unroll
    for (int c = 0; c < 8; ++c) acc += hpart[tid][c];
    float res;
    if (tid == 0)      res = sparams[2] + acc + sol_b[0];
    else if (tid < 3)  res = sparams[tid - 1] + acc + tr_b[tid - 1];
    else if (tid < 5)  res = sparams[tid] * __builtin_amdgcn_exp2f(LOG2E * (acc + sc_b[tid - 3]));
    else               res = sparams[5] + acc + tf_b[0];
    out[i * 6 + tid] = res;
  }
}

}  // namespace

extern "C" void kernel_launch(void* const* d_in, const int* in_sizes, int n_in,
                              void* d_out, int out_size, void* d_ws, size_t ws_size,
                              hipStream_t stream) {
  const float* means     = (const float*)d_in[0];
  const float* uu        = (const float*)d_in[1];
  const float* scaling   = (const float*)d_in[2];
  const float* transform = (const float*)d_in[3];
  const float* conv_w    = (const float*)d_in[4];
  const float* conv_b    = (const float*)d_in[5];
  const float* emb_w     = (const float*)d_in[6];
  const float* emb_b     = (const float*)d_in[7];
  const float* lin1_w    = (const float*)d_in[8];
  const float* lin1_b    = (const float*)d_in[9];
  const float* sol_w     = (const float*)d_in[10];
  const float* sol_b     = (const float*)d_in[11];
  const float* tr_w      = (const float*)d_in[12];
  const float* tr_b      = (const float*)d_in[13];
  const float* sc_w      = (const float*)d_in[14];
  const float* sc_b      = (const float*)d_in[15];
  const float* tf_w      = (const float*)d_in[16];
  const float* tf_b      = (const float*)d_in[17];

  float* cwT = (float*)d_ws;                       // 15000 floats (60 KB)
  float* img = (float*)d_ws + 16384;               // 1024*75 floats (300 KB)
  float* out = (float*)d_out;

  k_prep<<<59, 256, 0, stream>>>(conv_w, cwT);
  k_mixture<<<400, 256, 0, stream>>>(means, uu, scaling, transform, img);
  k_net<<<1024, 256, 0, stream>>>(img, means, uu, scaling, transform,
                                  cwT, conv_b, emb_w, emb_b, lin1_w, lin1_b,
                                  sol_w, sol_b, tr_w, tr_b, sc_w, sc_b, tf_w, tf_b,
                                  out);
}

// Round 3
// 111.857 us; speedup vs baseline: 1.1498x; 1.0878x over previous
//
#include <hip/hip_runtime.h>
#include <math.h>

// Model_21775484190778: Gaussian-splat PDE step. N=1024, K=5 -> S=25600 samples.
// R3: single fused kernel (mixture + net per gaussian-block), perfect 4-waves/SIMD
// balance, img stays in LDS. k_prep transposes conv_w for coalesced net reads.

namespace {

constexpr int NG = 1024;
constexpr float DXF = 2.0f / 31.0f;
constexpr float NHALF_LOG2E = -0.72134752044448170367f;  // -0.5 * log2(e)
constexpr float TWO_LOG2E   = 2.88539008177792681472f;   //  2.0 * log2(e)
constexpr float LOG2E       = 1.44269504088896340736f;

__device__ __forceinline__ float fast_tanh(float x) {
  x = fminf(9.0f, fmaxf(-9.0f, x));
  float t = __builtin_amdgcn_exp2f(TWO_LOG2E * x);
  return (t - 1.0f) * __builtin_amdgcn_rcpf(t + 1.0f);
}

// ---------------------------------------------------------------------------
// Prep: transpose conv_w (4,50,75) -> cwT (4,75,50): conv reads lane-coalesced.
// ---------------------------------------------------------------------------
__global__ __launch_bounds__(256) void k_prep(
    const float* __restrict__ conv_w, float* __restrict__ cwT)
{
  int idx = blockIdx.x * 256 + threadIdx.x;   // (m,c,o)
  if (idx < 4 * 75 * 50) {
    int m = idx / 3750, r = idx - m * 3750;
    int c = r / 50, o = r - c * 50;
    cwT[idx] = conv_w[(m * 50 + o) * 75 + c];
  }
}

// ---------------------------------------------------------------------------
// Fused kernel: block i = gaussian i.
// Phase 1 (mixture): 250 threads = 25 samples x 10 gaussian-chunks (~102 each);
//   gaussian table (conics) staged in LDS; chunk index spans <=3 values/wave
//   -> <=3-way LDS broadcast (free-ish).
// Phase 2 (net): identical to R2 k_net, but img comes straight from LDS.
// ---------------------------------------------------------------------------
__global__ __launch_bounds__(256) void k_fused(
    const float* __restrict__ means, const float* __restrict__ uu,
    const float* __restrict__ scaling, const float* __restrict__ transform,
    const float* __restrict__ cwT, const float* __restrict__ conv_b,
    const float* __restrict__ emb_w, const float* __restrict__ emb_b,
    const float* __restrict__ lin1_w, const float* __restrict__ lin1_b,
    const float* __restrict__ sol_w, const float* __restrict__ sol_b,
    const float* __restrict__ tr_w, const float* __restrict__ tr_b,
    const float* __restrict__ sc_w, const float* __restrict__ sc_b,
    const float* __restrict__ tf_w, const float* __restrict__ tf_b,
    float* __restrict__ out)
{
  __shared__ float4 gp[NG];        // mx, my, a, b
  __shared__ float2 gq[NG];        // c, u
  __shared__ float r_us[10][25];
  __shared__ float r_pde[10][25];
  __shared__ float simg[75];       // [3][25]: u_s, pde, mask
  __shared__ float sparams[6];     // mx, my, u, s0, s1, t0
  __shared__ float h[320];
  __shared__ float h2[320];
  __shared__ float hpart[6][8];

  const int i = blockIdx.x;
  const int tid = threadIdx.x;

  // Stage gaussian table with conics:
  // L=[[s0,0],[t0,s1]]: a=(t0^2+s1^2)/(s0^2 s1^2), b=-t0/(s0 s1^2), c=1/s1^2
  for (int g = tid; g < NG; g += 256) {
    float mx = means[2 * g], my = means[2 * g + 1];
    float s0 = scaling[2 * g], s1 = scaling[2 * g + 1];
    float t0 = transform[g];
    float cc  = 1.0f / (s1 * s1);
    float is0 = 1.0f / s0;
    float bb  = -t0 * cc * is0;
    float aa  = (t0 * t0 * cc + 1.0f) * is0 * is0;
    gp[g] = make_float4(mx, my, aa, bb);
    gq[g] = make_float2(cc, uu[g]);
  }
  if (tid < 6) {
    float v;
    if (tid < 2)       v = means[2 * i + tid];
    else if (tid == 2) v = uu[i];
    else if (tid < 5)  v = scaling[2 * i + (tid - 3)];
    else               v = transform[i];
    sparams[tid] = v;
  }
  __syncthreads();

  // ---- Phase 1: mixture for this gaussian's 25 samples ----
  if (tid < 250) {
    const int c = tid / 25;            // chunk 0..9
    const int s = tid - c * 25;        // sample 0..24
    const int kx = s / 5, ky = s - kx * 5;
    const float sx = means[2 * i]     + (float)(kx - 2) * DXF;  // uniform s_load
    const float sy = means[2 * i + 1] + (float)(ky - 2) * DXF;
    const int base = (c < 4) ? 103 * c : 412 + 102 * (c - 4);
    const int len  = (c < 4) ? 103 : 102;
    float us = 0.0f, pde = 0.0f;
#pragma unroll 4
    for (int j = 0; j < len; ++j) {
      const int g = base + j;
      float4 p  = gp[g];
      float2 qv = gq[g];
      float dx = sx - p.x, dy = sy - p.y;
      float a = p.z, b = p.w, cc = qv.x;
      float Cd0 = a * dx + b * dy;
      float Cd1 = b * dx + cc * dy;
      float q   = dx * Cd0 + dy * Cd1;
      float w   = qv.y * __builtin_amdgcn_exp2f(NHALF_LOG2E * q);
      us  += w;
      pde += w * (Cd0 * Cd0 + Cd1 * Cd1 - (a + cc));
    }
    r_us[c][s]  = us;
    r_pde[c][s] = pde;
  }
  __syncthreads();

  if (tid < 25) {
    float U = 0.0f, P = 0.0f;
#pragma unroll
    for (int c = 0; c < 10; ++c) { U += r_us[c][tid]; P += r_pde[c][tid]; }
    const int kx = tid / 5, ky = tid - kx * 5;
    const float sx = sparams[0] + (float)(kx - 2) * DXF;
    const float sy = sparams[1] + (float)(ky - 2) * DXF;
    simg[tid]      = U;
    simg[25 + tid] = P;
    simg[50 + tid] = (fabsf(sx) < 1.0f && fabsf(sy) < 1.0f) ? 1.0f : 0.0f;
  }
  __syncthreads();

  // ---- Phase 2: the 4 stacked networks ----
  // conv: threads 0..199 -> y[m][o]; cwT reads coalesced over o
  if (tid < 200) {
    const int m = tid / 50, o = tid - m * 50;
    const float* w = cwT + m * 3750 + o;     // + c*50
    float acc = conv_b[m * 50 + o];
#pragma unroll
    for (int c = 0; c < 75; ++c) acc = fmaf(simg[c], w[c * 50], acc);
    h[m * 80 + o] = fast_tanh(acc);
  }
  // emb: threads 200..255 cover 120 outputs
  if (tid >= 200) {
    for (int e = tid - 200; e < 120; e += 56) {
      const int m = e / 30, q = e - m * 30;
      float acc = emb_b[m * 30 + q];
#pragma unroll
      for (int p = 0; p < 6; ++p) acc = fmaf(sparams[p], emb_w[(m * 6 + p) * 30 + q], acc);
      h[m * 80 + 50 + q] = fast_tanh(acc);
    }
  }
  __syncthreads();

  // lin1: 320 outputs; weight reads lane-coalesced over q
  for (int idx = tid; idx < 320; idx += 256) {
    const int m = idx / 80, q = idx - m * 80;
    const float* lw = lin1_w + m * 6400 + q;
    const float* hh = h + m * 80;
    float acc = lin1_b[m * 80 + q];
#pragma unroll 8
    for (int j = 0; j < 80; ++j) acc = fmaf(hh[j], lw[j * 80], acc);
    h2[idx] = fast_tanh(acc);
  }
  __syncthreads();

  // heads: 48 threads = 6 outputs x 8 chunks of 10
  if (tid < 48) {
    const int o = tid >> 3, c8 = tid & 7;
    const int m = (o == 0) ? 0 : (o < 3) ? 1 : (o < 5) ? 2 : 3;
    const float* wp; int stride;
    if (o == 0)      { wp = sol_w;            stride = 1; }
    else if (o < 3)  { wp = tr_w + (o - 1);   stride = 2; }
    else if (o < 5)  { wp = sc_w + (o - 3);   stride = 2; }
    else             { wp = tf_w;             stride = 1; }
    const float* hh = h2 + m * 80;
    float acc = 0.0f;
    const int j0 = c8 * 10;
#pragma unroll
    for (int j = 0; j < 10; ++j) acc = fmaf(hh[j0 + j], wp[(j0 + j) * stride], acc);
    hpart[o][c8] = acc;
  }
  __syncthreads();

  if (tid < 6) {
    float acc = 0.0f;
#pragma unroll
    for (int c = 0; c < 8; ++c) acc += hpart[tid][c];
    float res;
    if (tid == 0)      res = sparams[2] + acc + sol_b[0];
    else if (tid < 3)  res = sparams[tid - 1] + acc + tr_b[tid - 1];
    else if (tid < 5)  res = sparams[tid] * __builtin_amdgcn_exp2f(LOG2E * (acc + sc_b[tid - 3]));
    else               res = sparams[5] + acc + tf_b[0];
    out[i * 6 + tid] = res;
  }
}

}  // namespace

extern "C" void kernel_launch(void* const* d_in, const int* in_sizes, int n_in,
                              void* d_out, int out_size, void* d_ws, size_t ws_size,
                              hipStream_t stream) {
  const float* means     = (const float*)d_in[0];
  const float* uu        = (const float*)d_in[1];
  const float* scaling   = (const float*)d_in[2];
  const float* transform = (const float*)d_in[3];
  const float* conv_w    = (const float*)d_in[4];
  const float* conv_b    = (const float*)d_in[5];
  const float* emb_w     = (const float*)d_in[6];
  const float* emb_b     = (const float*)d_in[7];
  const float* lin1_w    = (const float*)d_in[8];
  const float* lin1_b    = (const float*)d_in[9];
  const float* sol_w     = (const float*)d_in[10];
  const float* sol_b     = (const float*)d_in[11];
  const float* tr_w      = (const float*)d_in[12];
  const float* tr_b      = (const float*)d_in[13];
  const float* sc_w      = (const float*)d_in[14];
  const float* sc_b      = (const float*)d_in[15];
  const float* tf_w      = (const float*)d_in[16];
  const float* tf_b      = (const float*)d_in[17];

  float* cwT = (float*)d_ws;                 // 15000 floats (60 KB)
  float* out = (float*)d_out;

  k_prep<<<59, 256, 0, stream>>>(conv_w, cwT);
  k_fused<<<1024, 256, 0, stream>>>(means, uu, scaling, transform,
                                    cwT, conv_b, emb_w, emb_b, lin1_w, lin1_b,
                                    sol_w, sol_b, tr_w, tr_b, sc_w, sc_b, tf_w, tf_b,
                                    out);
}

// Round 4
// 101.844 us; speedup vs baseline: 1.2629x; 1.0983x over previous
//
#include <hip/hip_runtime.h>
#include <math.h>

// Model_21775484190778: Gaussian-splat PDE step. N=1024, K=5 -> S=25600 samples.
// R4: adaptive gaussian culling in the fused kernel. Each block's 25 samples sit
// within +-2DX of mean_i; gaussian j can only contribute if
//   d_lb^2 <= 80 * trace(cov_j)   (q >= d^2/lambda_max(cov) >= d^2/trace(cov);
//   exp(-40)*[pde amp ~1e6] ~ 4e-12 -- below fp32 rounding of the kept sum).
// Survivors (~70 of 1024 for this input) compacted into LDS, then evaluated.

namespace {

constexpr int NG = 1024;
constexpr float DXF = 2.0f / 31.0f;
constexpr float NHALF_LOG2E = -0.72134752044448170367f;  // -0.5 * log2(e)
constexpr float TWO_LOG2E   = 2.88539008177792681472f;   //  2.0 * log2(e)
constexpr float LOG2E       = 1.44269504088896340736f;
constexpr float QCUT        = 80.0f;                      // exp(-40) cutoff

__device__ __forceinline__ float fast_tanh(float x) {
  x = fminf(9.0f, fmaxf(-9.0f, x));
  float t = __builtin_amdgcn_exp2f(TWO_LOG2E * x);
  return (t - 1.0f) * __builtin_amdgcn_rcpf(t + 1.0f);
}

// ---------------------------------------------------------------------------
// Prep: transpose conv_w (4,50,75) -> cwT (4,75,50): conv reads lane-coalesced.
// ---------------------------------------------------------------------------
__global__ __launch_bounds__(256) void k_prep(
    const float* __restrict__ conv_w, float* __restrict__ cwT)
{
  int idx = blockIdx.x * 256 + threadIdx.x;   // (m,c,o)
  if (idx < 4 * 75 * 50) {
    int m = idx / 3750, r = idx - m * 3750;
    int c = r / 50, o = r - c * 50;
    cwT[idx] = conv_w[(m * 50 + o) * 75 + c];
  }
}

// ---------------------------------------------------------------------------
// Fused kernel: block i = gaussian i.
// Phase 1: cull+compact survivors into LDS, evaluate 25 samples x cnt.
// Phase 2: 4 stacked networks (conv via transposed cwT, lin1, heads).
// ---------------------------------------------------------------------------
__global__ __launch_bounds__(256) void k_fused(
    const float* __restrict__ means, const float* __restrict__ uu,
    const float* __restrict__ scaling, const float* __restrict__ transform,
    const float* __restrict__ cwT, const float* __restrict__ conv_b,
    const float* __restrict__ emb_w, const float* __restrict__ emb_b,
    const float* __restrict__ lin1_w, const float* __restrict__ lin1_b,
    const float* __restrict__ sol_w, const float* __restrict__ sol_b,
    const float* __restrict__ tr_w, const float* __restrict__ tr_b,
    const float* __restrict__ sc_w, const float* __restrict__ sc_b,
    const float* __restrict__ tf_w, const float* __restrict__ tf_b,
    float* __restrict__ out)
{
  __shared__ float4 sgp[NG];       // survivors: mx, my, a, b
  __shared__ float2 sgq[NG];       // survivors: c, u
  __shared__ int s_cnt;
  __shared__ float r_us[10][25];
  __shared__ float r_pde[10][25];
  __shared__ float simg[75];       // [3][25]: u_s, pde, mask
  __shared__ float sparams[6];     // mx, my, u, s0, s1, t0
  __shared__ float h[320];
  __shared__ float h2[320];
  __shared__ float hpart[6][8];

  const int i = blockIdx.x;
  const int tid = threadIdx.x;

  if (tid == 0) s_cnt = 0;
  if (tid < 6) {
    float v;
    if (tid < 2)       v = means[2 * i + tid];
    else if (tid == 2) v = uu[i];
    else if (tid < 5)  v = scaling[2 * i + (tid - 3)];
    else               v = transform[i];
    sparams[tid] = v;
  }
  __syncthreads();

  // ---- Cull + compact ----
  const float mxi = sparams[0], myi = sparams[1];
  for (int g = tid; g < NG; g += 256) {
    float gmx = means[2 * g], gmy = means[2 * g + 1];
    float s0 = scaling[2 * g], s1 = scaling[2 * g + 1];
    float t0 = transform[g];
    float ex = fmaxf(fabsf(gmx - mxi) - 2.0f * DXF, 0.0f);
    float ey = fmaxf(fabsf(gmy - myi) - 2.0f * DXF, 0.0f);
    float tr = s0 * s0 + s1 * s1 + t0 * t0;
    if (ex * ex + ey * ey <= QCUT * tr) {
      int idx = atomicAdd(&s_cnt, 1);
      // conic of L=[[s0,0],[t0,s1]]: a=(t0^2+s1^2)/(s0^2 s1^2), b=-t0/(s0 s1^2), c=1/s1^2
      float cc  = 1.0f / (s1 * s1);
      float is0 = 1.0f / s0;
      float bb  = -t0 * cc * is0;
      float aa  = (t0 * t0 * cc + 1.0f) * is0 * is0;
      sgp[idx] = make_float4(gmx, gmy, aa, bb);
      sgq[idx] = make_float2(cc, uu[g]);
    }
  }
  __syncthreads();

  // ---- Evaluate 25 samples x cnt survivors ----
  const int cnt = s_cnt;
  if (tid < 250) {
    const int c = tid / 25;            // chunk 0..9
    const int s = tid - c * 25;        // sample 0..24
    const int kx = s / 5, ky = s - kx * 5;
    const float sx = mxi + (float)(kx - 2) * DXF;
    const float sy = myi + (float)(ky - 2) * DXF;
    float us = 0.0f, pde = 0.0f;
    for (int j = c; j < cnt; j += 10) {
      float4 p  = sgp[j];
      float2 qv = sgq[j];
      float dx = sx - p.x, dy = sy - p.y;
      float a = p.z, b = p.w, cc = qv.x;
      float Cd0 = a * dx + b * dy;
      float Cd1 = b * dx + cc * dy;
      float q   = dx * Cd0 + dy * Cd1;
      float w   = qv.y * __builtin_amdgcn_exp2f(NHALF_LOG2E * q);
      us  += w;
      pde += w * (Cd0 * Cd0 + Cd1 * Cd1 - (a + cc));
    }
    r_us[c][s]  = us;
    r_pde[c][s] = pde;
  }
  __syncthreads();

  if (tid < 25) {
    float U = 0.0f, P = 0.0f;
#pragma unroll
    for (int c = 0; c < 10; ++c) { U += r_us[c][tid]; P += r_pde[c][tid]; }
    const int kx = tid / 5, ky = tid - kx * 5;
    const float sx = mxi + (float)(kx - 2) * DXF;
    const float sy = myi + (float)(ky - 2) * DXF;
    simg[tid]      = U;
    simg[25 + tid] = P;
    simg[50 + tid] = (fabsf(sx) < 1.0f && fabsf(sy) < 1.0f) ? 1.0f : 0.0f;
  }
  __syncthreads();

  // ---- Phase 2: the 4 stacked networks ----
  if (tid < 200) {
    const int m = tid / 50, o = tid - m * 50;
    const float* w = cwT + m * 3750 + o;     // + c*50, lane-coalesced over o
    float acc = conv_b[m * 50 + o];
#pragma unroll
    for (int c = 0; c < 75; ++c) acc = fmaf(simg[c], w[c * 50], acc);
    h[m * 80 + o] = fast_tanh(acc);
  }
  if (tid >= 200) {
    for (int e = tid - 200; e < 120; e += 56) {
      const int m = e / 30, q = e - m * 30;
      float acc = emb_b[m * 30 + q];
#pragma unroll
      for (int p = 0; p < 6; ++p) acc = fmaf(sparams[p], emb_w[(m * 6 + p) * 30 + q], acc);
      h[m * 80 + 50 + q] = fast_tanh(acc);
    }
  }
  __syncthreads();

  for (int idx = tid; idx < 320; idx += 256) {
    const int m = idx / 80, q = idx - m * 80;
    const float* lw = lin1_w + m * 6400 + q;   // lane-coalesced over q
    const float* hh = h + m * 80;
    float acc = lin1_b[m * 80 + q];
#pragma unroll 8
    for (int j = 0; j < 80; ++j) acc = fmaf(hh[j], lw[j * 80], acc);
    h2[idx] = fast_tanh(acc);
  }
  __syncthreads();

  if (tid < 48) {
    const int o = tid >> 3, c8 = tid & 7;
    const int m = (o == 0) ? 0 : (o < 3) ? 1 : (o < 5) ? 2 : 3;
    const float* wp; int stride;
    if (o == 0)      { wp = sol_w;            stride = 1; }
    else if (o < 3)  { wp = tr_w + (o - 1);   stride = 2; }
    else if (o < 5)  { wp = sc_w + (o - 3);   stride = 2; }
    else             { wp = tf_w;             stride = 1; }
    const float* hh = h2 + m * 80;
    float acc = 0.0f;
    const int j0 = c8 * 10;
#pragma unroll
    for (int j = 0; j < 10; ++j) acc = fmaf(hh[j0 + j], wp[(j0 + j) * stride], acc);
    hpart[o][c8] = acc;
  }
  __syncthreads();

  if (tid < 6) {
    float acc = 0.0f;
#pragma unroll
    for (int c = 0; c < 8; ++c) acc += hpart[tid][c];
    float res;
    if (tid == 0)      res = sparams[2] + acc + sol_b[0];
    else if (tid < 3)  res = sparams[tid - 1] + acc + tr_b[tid - 1];
    else if (tid < 5)  res = sparams[tid] * __builtin_amdgcn_exp2f(LOG2E * (acc + sc_b[tid - 3]));
    else               res = sparams[5] + acc + tf_b[0];
    out[i * 6 + tid] = res;
  }
}

}  // namespace

extern "C" void kernel_launch(void* const* d_in, const int* in_sizes, int n_in,
                              void* d_out, int out_size, void* d_ws, size_t ws_size,
                              hipStream_t stream) {
  const float* means     = (const float*)d_in[0];
  const float* uu        = (const float*)d_in[1];
  const float* scaling   = (const float*)d_in[2];
  const float* transform = (const float*)d_in[3];
  const float* conv_w    = (const float*)d_in[4];
  const float* conv_b    = (const float*)d_in[5];
  const float* emb_w     = (const float*)d_in[6];
  const float* emb_b     = (const float*)d_in[7];
  const float* lin1_w    = (const float*)d_in[8];
  const float* lin1_b    = (const float*)d_in[9];
  const float* sol_w     = (const float*)d_in[10];
  const float* sol_b     = (const float*)d_in[11];
  const float* tr_w      = (const float*)d_in[12];
  const float* tr_b      = (const float*)d_in[13];
  const float* sc_w      = (const float*)d_in[14];
  const float* sc_b      = (const float*)d_in[15];
  const float* tf_w      = (const float*)d_in[16];
  const float* tf_b      = (const float*)d_in[17];

  float* cwT = (float*)d_ws;                 // 15000 floats (60 KB)
  float* out = (float*)d_out;

  k_prep<<<59, 256, 0, stream>>>(conv_w, cwT);
  k_fused<<<1024, 256, 0, stream>>>(means, uu, scaling, transform,
                                    cwT, conv_b, emb_w, emb_b, lin1_w, lin1_b,
                                    sol_w, sol_b, tr_w, tr_b, sc_w, sc_b, tf_w, tf_b,
                                    out);
}

// Round 5
// 98.233 us; speedup vs baseline: 1.3093x; 1.0368x over previous
//
#include <hip/hip_runtime.h>
#include <math.h>

// Model_21775484190778: Gaussian-splat PDE step. N=1024, K=5 -> S=25600 samples.
// R5: single kernel. G=4 gaussians per block (256 blocks x 512 thr = 1/CU):
//  - weight traffic amortized 4x (thread owns (m,out), loops g inside the load)
//  - conv_w staged in LDS (58.6 KB; (11o+c)%32 read pattern is conflict-free)
//    -> k_prep transpose launch eliminated
//  - adaptive cull vs union bbox of the 4 means (+2DX), survivors ~110.

namespace {

constexpr int NG = 1024;
constexpr int G  = 4;                                    // gaussians per block
constexpr float DXF = 2.0f / 31.0f;
constexpr float NHALF_LOG2E = -0.72134752044448170367f;  // -0.5 * log2(e)
constexpr float TWO_LOG2E   = 2.88539008177792681472f;   //  2.0 * log2(e)
constexpr float LOG2E       = 1.44269504088896340736f;
constexpr float QCUT        = 80.0f;                     // exp(-40) cutoff

__device__ __forceinline__ float fast_tanh(float x) {
  x = fminf(9.0f, fmaxf(-9.0f, x));
  float t = __builtin_amdgcn_exp2f(TWO_LOG2E * x);
  return (t - 1.0f) * __builtin_amdgcn_rcpf(t + 1.0f);
}

__global__ __launch_bounds__(512) void k_fused(
    const float* __restrict__ means, const float* __restrict__ uu,
    const float* __restrict__ scaling, const float* __restrict__ transform,
    const float* __restrict__ conv_w, const float* __restrict__ conv_b,
    const float* __restrict__ emb_w, const float* __restrict__ emb_b,
    const float* __restrict__ lin1_w, const float* __restrict__ lin1_b,
    const float* __restrict__ sol_w, const float* __restrict__ sol_b,
    const float* __restrict__ tr_w, const float* __restrict__ tr_b,
    const float* __restrict__ sc_w, const float* __restrict__ sc_b,
    const float* __restrict__ tf_w, const float* __restrict__ tf_b,
    float* __restrict__ out)
{
  __shared__ float  scw[4 * 50 * 75];   // conv_w copy (m,o,c) 58.6 KB
  __shared__ float4 sgp[NG];            // survivors: mx, my, a, b (16 KB)
  __shared__ float2 sgq[NG];            // survivors: c, u         (8 KB)
  __shared__ int s_cnt;
  __shared__ float r_us[5][100];
  __shared__ float r_pde[5][100];
  __shared__ float simg[G][75];         // per-g [3][25]
  __shared__ float sparams[G][6];       // mx, my, u, s0, s1, t0
  __shared__ float h[G][320];
  __shared__ float h2[G][320];
  __shared__ float hpart[G][6][8];

  const int i0 = blockIdx.x * G;        // first gaussian of this block
  const int tid = threadIdx.x;

  // ---- stage conv_w into LDS (coalesced float4) ----
  {
    const float4* src = (const float4*)conv_w;
    float4* dst = (float4*)scw;
    for (int idx = tid; idx < 3750; idx += 512) dst[idx] = src[idx];
  }
  if (tid == 0) s_cnt = 0;
  if (tid < G * 6) {
    const int g = tid / 6, f = tid - g * 6, ig = i0 + g;
    float v;
    if (f < 2)       v = means[2 * ig + f];
    else if (f == 2) v = uu[ig];
    else if (f < 5)  v = scaling[2 * ig + (f - 3)];
    else             v = transform[ig];
    sparams[g][f] = v;
  }
  __syncthreads();

  // ---- union sample bbox of the G gaussians ----
  float lox = 1e30f, hix = -1e30f, loy = 1e30f, hiy = -1e30f;
#pragma unroll
  for (int g = 0; g < G; ++g) {
    lox = fminf(lox, sparams[g][0]); hix = fmaxf(hix, sparams[g][0]);
    loy = fminf(loy, sparams[g][1]); hiy = fmaxf(hiy, sparams[g][1]);
  }
  lox -= 2.0f * DXF; hix += 2.0f * DXF;
  loy -= 2.0f * DXF; hiy += 2.0f * DXF;

  // ---- cull + compact survivors ----
  const float2* means2 = (const float2*)means;
  const float2* scal2  = (const float2*)scaling;
  for (int g = tid; g < NG; g += 512) {
    float2 mg = means2[g];
    float2 sg = scal2[g];
    float t0 = transform[g];
    float ex = fmaxf(fmaxf(lox - mg.x, mg.x - hix), 0.0f);
    float ey = fmaxf(fmaxf(loy - mg.y, mg.y - hiy), 0.0f);
    float tr = sg.x * sg.x + sg.y * sg.y + t0 * t0;
    if (ex * ex + ey * ey <= QCUT * tr) {
      int idx = atomicAdd(&s_cnt, 1);
      // conic of L=[[s0,0],[t0,s1]]: a=(t0^2+s1^2)/(s0^2 s1^2), b=-t0/(s0 s1^2), c=1/s1^2
      float cc  = 1.0f / (sg.y * sg.y);
      float is0 = 1.0f / sg.x;
      float bb  = -t0 * cc * is0;
      float aa  = (t0 * t0 * cc + 1.0f) * is0 * is0;
      sgp[idx] = make_float4(mg.x, mg.y, aa, bb);
      sgq[idx] = make_float2(cc, uu[g]);
    }
  }
  __syncthreads();

  // ---- evaluate G*25 = 100 samples x cnt survivors (5 chunks) ----
  const int cnt = s_cnt;
  if (tid < 500) {
    const int c = tid / 100;              // chunk 0..4
    const int s = tid - c * 100;          // sample 0..99 (g = s/25, k = s%25)
    const int g = s / 25, k = s - g * 25;
    const int kx = k / 5, ky = k - kx * 5;
    const float sx = sparams[g][0] + (float)(kx - 2) * DXF;
    const float sy = sparams[g][1] + (float)(ky - 2) * DXF;
    float us = 0.0f, pde = 0.0f;
    for (int j = c; j < cnt; j += 5) {
      float4 p  = sgp[j];
      float2 qv = sgq[j];
      float dx = sx - p.x, dy = sy - p.y;
      float a = p.z, b = p.w, cc = qv.x;
      float Cd0 = a * dx + b * dy;
      float Cd1 = b * dx + cc * dy;
      float q   = dx * Cd0 + dy * Cd1;
      float w   = qv.y * __builtin_amdgcn_exp2f(NHALF_LOG2E * q);
      us  += w;
      pde += w * (Cd0 * Cd0 + Cd1 * Cd1 - (a + cc));
    }
    r_us[c][s]  = us;
    r_pde[c][s] = pde;
  }
  __syncthreads();

  if (tid < 100) {
    const int g = tid / 25, k = tid - g * 25;
    float U = 0.0f, P = 0.0f;
#pragma unroll
    for (int c = 0; c < 5; ++c) { U += r_us[c][tid]; P += r_pde[c][tid]; }
    const int kx = k / 5, ky = k - kx * 5;
    const float sx = sparams[g][0] + (float)(kx - 2) * DXF;
    const float sy = sparams[g][1] + (float)(ky - 2) * DXF;
    simg[g][k]      = U;
    simg[g][25 + k] = P;
    simg[g][50 + k] = (fabsf(sx) < 1.0f && fabsf(sy) < 1.0f) ? 1.0f : 0.0f;
  }
  __syncthreads();

  // ---- net phase: thread owns (m,output), loops g inside the weight load ----
  // conv: 200 threads -> (m,o); weight from LDS ((11o+c)%32: conflict-free)
  if (tid < 200) {
    const int m = tid / 50, o = tid - m * 50;
    const float* w = scw + (m * 50 + o) * 75;
    const float bb = conv_b[m * 50 + o];
    float acc[G] = {bb, bb, bb, bb};
#pragma unroll 5
    for (int c = 0; c < 75; ++c) {
      float wv = w[c];
#pragma unroll
      for (int g = 0; g < G; ++g) acc[g] = fmaf(simg[g][c], wv, acc[g]);
    }
#pragma unroll
    for (int g = 0; g < G; ++g) h[g][m * 80 + o] = fast_tanh(acc[g]);
  }
  // emb: threads 200..319 -> (m,q) of 4x30
  if (tid >= 200 && tid < 320) {
    const int e = tid - 200;
    const int m = e / 30, q = e - m * 30;
    const float bb = emb_b[m * 30 + q];
    float acc[G] = {bb, bb, bb, bb};
#pragma unroll
    for (int p = 0; p < 6; ++p) {
      float wv = emb_w[(m * 6 + p) * 30 + q];
#pragma unroll
      for (int g = 0; g < G; ++g) acc[g] = fmaf(sparams[g][p], wv, acc[g]);
    }
#pragma unroll
    for (int g = 0; g < G; ++g) h[g][m * 80 + 50 + q] = fast_tanh(acc[g]);
  }
  __syncthreads();

  // lin1: 320 threads -> (m,q); weight global coalesced over q, read once for 4 g
  if (tid < 320) {
    const int m = tid / 80, q = tid - m * 80;
    const float* lw = lin1_w + m * 6400 + q;
    const float bb = lin1_b[m * 80 + q];
    float acc[G] = {bb, bb, bb, bb};
#pragma unroll 8
    for (int j = 0; j < 80; ++j) {
      float wv = lw[j * 80];
#pragma unroll
      for (int g = 0; g < G; ++g) acc[g] = fmaf(h[g][m * 80 + j], wv, acc[g]);
    }
#pragma unroll
    for (int g = 0; g < G; ++g) h2[g][m * 80 + q] = fast_tanh(acc[g]);
  }
  __syncthreads();

  // heads: 192 threads = g x 6 outputs x 8 chunks of 10
  if (tid < 192) {
    const int g = tid / 48, t = tid - g * 48;
    const int o = t >> 3, c8 = t & 7;
    const int m = (o == 0) ? 0 : (o < 3) ? 1 : (o < 5) ? 2 : 3;
    const float* wp; int stride;
    if (o == 0)      { wp = sol_w;            stride = 1; }
    else if (o < 3)  { wp = tr_w + (o - 1);   stride = 2; }
    else if (o < 5)  { wp = sc_w + (o - 3);   stride = 2; }
    else             { wp = tf_w;             stride = 1; }
    const float* hh = h2[g] + m * 80;
    float acc = 0.0f;
    const int j0 = c8 * 10;
#pragma unroll
    for (int j = 0; j < 10; ++j) acc = fmaf(hh[j0 + j], wp[(j0 + j) * stride], acc);
    hpart[g][o][c8] = acc;
  }
  __syncthreads();

  if (tid < G * 6) {
    const int g = tid / 6, o = tid - g * 6;
    float acc = 0.0f;
#pragma unroll
    for (int c = 0; c < 8; ++c) acc += hpart[g][o][c];
    float res;
    if (o == 0)      res = sparams[g][2] + acc + sol_b[0];
    else if (o < 3)  res = sparams[g][o - 1] + acc + tr_b[o - 1];
    else if (o < 5)  res = sparams[g][o] * __builtin_amdgcn_exp2f(LOG2E * (acc + sc_b[o - 3]));
    else             res = sparams[g][5] + acc + tf_b[0];
    out[(i0 + g) * 6 + o] = res;
  }
}

}  // namespace

extern "C" void kernel_launch(void* const* d_in, const int* in_sizes, int n_in,
                              void* d_out, int out_size, void* d_ws, size_t ws_size,
                              hipStream_t stream) {
  const float* means     = (const float*)d_in[0];
  const float* uu        = (const float*)d_in[1];
  const float* scaling   = (const float*)d_in[2];
  const float* transform = (const float*)d_in[3];
  const float* conv_w    = (const float*)d_in[4];
  const float* conv_b    = (const float*)d_in[5];
  const float* emb_w     = (const float*)d_in[6];
  const float* emb_b     = (const float*)d_in[7];
  const float* lin1_w    = (const float*)d_in[8];
  const float* lin1_b    = (const float*)d_in[9];
  const float* sol_w     = (const float*)d_in[10];
  const float* sol_b     = (const float*)d_in[11];
  const float* tr_w      = (const float*)d_in[12];
  const float* tr_b      = (const float*)d_in[13];
  const float* sc_w      = (const float*)d_in[14];
  const float* sc_b      = (const float*)d_in[15];
  const float* tf_w      = (const float*)d_in[16];
  const float* tf_b      = (const float*)d_in[17];

  float* out = (float*)d_out;

  k_fused<<<NG / G, 512, 0, stream>>>(means, uu, scaling, transform,
                                      conv_w, conv_b, emb_w, emb_b, lin1_w, lin1_b,
                                      sol_w, sol_b, tr_w, tr_b, sc_w, sc_b, tf_w, tf_b,
                                      out);
}